// Round 4
// baseline (138.019 us; speedup 1.0000x reference)
//
#include <hip/hip_runtime.h>
#include <hip/hip_bf16.h>

typedef short s16x8 __attribute__((ext_vector_type(8)));
typedef float f32x4 __attribute__((ext_vector_type(4)));

#define M_DIM   128
#define K_DIM   131072           // C*W*H = 512*16*16
#define NSPLIT  256              // split-K blocks -> 1 block/CU
#define KC      (K_DIM / NSPLIT) // 512 per block
#define BK      64               // K per LDS step
#define NSTEP   (KC / BK)        // 8
#define THREADS 512
#define OUT_N   (M_DIM * M_DIM)  // 16384
#define WS_PART_BYTES ((size_t)NSPLIT * OUT_N * 2)   // 8 MiB bf16 partials

__device__ __forceinline__ short f2bf(float f) {
    unsigned u = __builtin_bit_cast(unsigned, f);
    u += 0x7fffu + ((u >> 16) & 1u);   // round-to-nearest-even
    return (short)(u >> 16);
}
__device__ __forceinline__ float bf2f(unsigned short h) {
    unsigned u = ((unsigned)h) << 16;
    return __builtin_bit_cast(float, u);
}
__device__ __forceinline__ s16x8 cvt8(float4 a, float4 b) {
    s16x8 r;
    r[0] = f2bf(a.x); r[1] = f2bf(a.y); r[2] = f2bf(a.z); r[3] = f2bf(a.w);
    r[4] = f2bf(b.x); r[5] = f2bf(b.y); r[6] = f2bf(b.z); r[7] = f2bf(b.w);
    return r;
}

// Fused: split-K GEMM partials -> grid barrier -> per-block reduction.
// 256 blocks, 1/CU; depth-2 global->reg prefetch; bf16 LDS tiles + MFMA.
__global__ __launch_bounds__(THREADS) void gemm_fused(
    const float* __restrict__ x, const float* __restrict__ y,
    const float* __restrict__ kern,
    unsigned short* __restrict__ ws, unsigned int* __restrict__ counter,
    float* __restrict__ out)
{
    __shared__ __align__(16) short lds[2][2][M_DIM][BK];   // 64 KiB

    const int t    = threadIdx.x;
    const long kb0 = (long)blockIdx.x * KC;

    const int srow = t >> 3;
    const int sg   = t & 7;
    const int wofs = (sg ^ (srow & 7)) * 8;   // swizzle ((srow+64)&7 == srow&7)

    const float* xa = x + (size_t)srow        * K_DIM + kb0 + sg * 8;
    const float* xb = x + (size_t)(srow + 64) * K_DIM + kb0 + sg * 8;
    const float* ya = y + (size_t)srow        * K_DIM + kb0 + sg * 8;
    const float* yb = y + (size_t)(srow + 64) * K_DIM + kb0 + sg * 8;

    const int wave = t >> 6;
    const int lane = t & 63;
    const int wr   = wave >> 2;
    const int wc   = wave & 3;
    const int l15  = lane & 15;
    const int l4   = lane >> 4;

    f32x4 acc[4][2] = {};
    float4 A0,A1,A2,A3,A4,A5,A6,A7;
    float4 B0,B1,B2,B3,B4,B5,B6,B7;

    #define STAGE_LOAD(R, kb)                                            \
        R##0 = *(const float4*)(xa + (kb)); R##1 = *(const float4*)(xa + (kb) + 4); \
        R##2 = *(const float4*)(xb + (kb)); R##3 = *(const float4*)(xb + (kb) + 4); \
        R##4 = *(const float4*)(ya + (kb)); R##5 = *(const float4*)(ya + (kb) + 4); \
        R##6 = *(const float4*)(yb + (kb)); R##7 = *(const float4*)(yb + (kb) + 4);

    #define STAGE_WRITE(R, buf)                                          \
        *(s16x8*)&lds[buf][0][srow     ][wofs] = cvt8(R##0, R##1);       \
        *(s16x8*)&lds[buf][0][srow + 64][wofs] = cvt8(R##2, R##3);       \
        *(s16x8*)&lds[buf][1][srow     ][wofs] = cvt8(R##4, R##5);       \
        *(s16x8*)&lds[buf][1][srow + 64][wofs] = cvt8(R##6, R##7);

    auto compute = [&](int buf) {
        #pragma unroll
        for (int ks = 0; ks < 2; ++ks) {
            s16x8 af[4], bf[2];
            const int g = ks * 4 + l4;
            #pragma unroll
            for (int m = 0; m < 4; ++m) {
                const int row = wr * 64 + m * 16 + l15;
                af[m] = *(const s16x8*)&lds[buf][0][row][(g ^ (row & 7)) * 8];
            }
            #pragma unroll
            for (int n = 0; n < 2; ++n) {
                const int row = wc * 32 + n * 16 + l15;
                bf[n] = *(const s16x8*)&lds[buf][1][row][(g ^ (row & 7)) * 8];
            }
            #pragma unroll
            for (int m = 0; m < 4; ++m)
                #pragma unroll
                for (int n = 0; n < 2; ++n)
                    acc[m][n] = __builtin_amdgcn_mfma_f32_16x16x32_bf16(
                        af[m], bf[n], acc[m][n], 0, 0, 0);
        }
    };

    STAGE_LOAD(A, 0)
    STAGE_LOAD(B, BK)
    STAGE_WRITE(A, 0)
    __syncthreads();

    #pragma unroll
    for (int s = 0; s < NSTEP; s += 2) {
        if (s + 2 < NSTEP) { STAGE_LOAD(A, (long)(s + 2) * BK) }
        compute(0);
        STAGE_WRITE(B, 1)
        __syncthreads();
        if (s + 3 < NSTEP) { STAGE_LOAD(B, (long)(s + 3) * BK) }
        compute(1);
        if (s + 2 < NSTEP) { STAGE_WRITE(A, 0) }
        __syncthreads();
    }

    // write bf16 partial tile; D frag: col=lane&15, row=(lane>>4)*4+reg
    {
        unsigned short* wp = ws + (size_t)blockIdx.x * OUT_N;
        #pragma unroll
        for (int m = 0; m < 4; ++m) {
            const int row = wr * 64 + m * 16 + l4 * 4;
            #pragma unroll
            for (int n = 0; n < 2; ++n) {
                const int col = wc * 32 + n * 16 + l15;
                #pragma unroll
                for (int r = 0; r < 4; ++r)
                    wp[(size_t)(row + r) * M_DIM + col] =
                        (unsigned short)f2bf(acc[m][n][r]);
            }
        }
    }

    // grid barrier (256 blocks, 1/CU; even 2-on-1-CU placement still runs:
    // 128 KiB LDS <= 160, 16 waves <= 32 -> no deadlock possible)
    __syncthreads();          // drains each wave's stores (vmcnt 0)
    __threadfence();          // agent release: buffer_wbl2 -> partials to L3
    if (t == 0) {
        __hip_atomic_fetch_add(counter, 1u, __ATOMIC_RELEASE,
                               __HIP_MEMORY_SCOPE_AGENT);
        while (__hip_atomic_load(counter, __ATOMIC_ACQUIRE,
                                 __HIP_MEMORY_SCOPE_AGENT) < NSPLIT)
            __builtin_amdgcn_s_sleep(8);
    }
    __syncthreads();
    __threadfence();          // acquire: buffer_inv -> phase-2 reads hit L3

    // phase 2: block b reduces outputs [64b, 64b+64) over 256 splits
    {
        float* red = (float*)lds;          // reuse LDS: [(sc*8+g)*8 + i]
        const int b  = blockIdx.x;
        const int g  = t & 7;              // 8 e-groups of 8 outputs
        const int sc = t >> 3;             // 64 s-chunks of 4 splits
        const unsigned short* wp =
            ws + (size_t)(sc * 4) * OUT_N + b * 64 + g * 8;

        float a[8] = {};
        #pragma unroll
        for (int j = 0; j < 4; ++j) {
            uint4 v = *(const uint4*)(wp + (size_t)j * OUT_N);
            a[0] += bf2f((unsigned short)(v.x & 0xffff));
            a[1] += bf2f((unsigned short)(v.x >> 16));
            a[2] += bf2f((unsigned short)(v.y & 0xffff));
            a[3] += bf2f((unsigned short)(v.y >> 16));
            a[4] += bf2f((unsigned short)(v.z & 0xffff));
            a[5] += bf2f((unsigned short)(v.z >> 16));
            a[6] += bf2f((unsigned short)(v.w & 0xffff));
            a[7] += bf2f((unsigned short)(v.w >> 16));
        }
        #pragma unroll
        for (int i = 0; i < 8; ++i) red[(sc * 8 + g) * 8 + i] = a[i];
        __syncthreads();
        for (int off = 32; off > 0; off >>= 1) {
            if (sc < off) {
                #pragma unroll
                for (int i = 0; i < 8; ++i)
                    red[(sc * 8 + g) * 8 + i] +=
                        red[((sc + off) * 8 + g) * 8 + i];
            }
            __syncthreads();
        }
        if (t < 64) {
            // sc=0 slice: red[(g)*8 + i], g=t>>3, i=t&7
            const float scale = kern[0] * (1.0f / 512.0f);
            out[b * 64 + t] = red[t] * scale + 0.1f;
        }
    }
    #undef STAGE_LOAD
    #undef STAGE_WRITE
}

// ---------------- fallback (ws too small): init + atomic gemm
__global__ __launch_bounds__(THREADS) void gemm_atomic(
    const float* __restrict__ x, const float* __restrict__ y,
    const float* __restrict__ kern, float* __restrict__ out)
{
    __shared__ __align__(16) short lds[2][2][M_DIM][BK];
    const int t    = threadIdx.x;
    const long kb0 = (long)blockIdx.x * KC;
    const int srow = t >> 3, sg = t & 7;
    const int wofs = (sg ^ (srow & 7)) * 8;
    const float* xa = x + (size_t)srow        * K_DIM + kb0 + sg * 8;
    const float* xb = x + (size_t)(srow + 64) * K_DIM + kb0 + sg * 8;
    const float* ya = y + (size_t)srow        * K_DIM + kb0 + sg * 8;
    const float* yb = y + (size_t)(srow + 64) * K_DIM + kb0 + sg * 8;
    const int wave = t >> 6, lane = t & 63;
    const int wr = wave >> 2, wc = wave & 3, l15 = lane & 15, l4 = lane >> 4;
    f32x4 acc[4][2] = {};
    float4 A0,A1,A2,A3,A4,A5,A6,A7, B0,B1,B2,B3,B4,B5,B6,B7;
    #define STAGE_LOAD(R, kb)                                            \
        R##0 = *(const float4*)(xa + (kb)); R##1 = *(const float4*)(xa + (kb) + 4); \
        R##2 = *(const float4*)(xb + (kb)); R##3 = *(const float4*)(xb + (kb) + 4); \
        R##4 = *(const float4*)(ya + (kb)); R##5 = *(const float4*)(ya + (kb) + 4); \
        R##6 = *(const float4*)(yb + (kb)); R##7 = *(const float4*)(yb + (kb) + 4);
    #define STAGE_WRITE(R, buf)                                          \
        *(s16x8*)&lds[buf][0][srow     ][wofs] = cvt8(R##0, R##1);       \
        *(s16x8*)&lds[buf][0][srow + 64][wofs] = cvt8(R##2, R##3);       \
        *(s16x8*)&lds[buf][1][srow     ][wofs] = cvt8(R##4, R##5);       \
        *(s16x8*)&lds[buf][1][srow + 64][wofs] = cvt8(R##6, R##7);
    auto compute = [&](int buf) {
        #pragma unroll
        for (int ks = 0; ks < 2; ++ks) {
            s16x8 af[4], bf[2];
            const int g = ks * 4 + l4;
            #pragma unroll
            for (int m = 0; m < 4; ++m) {
                const int row = wr * 64 + m * 16 + l15;
                af[m] = *(const s16x8*)&lds[buf][0][row][(g ^ (row & 7)) * 8];
            }
            #pragma unroll
            for (int n = 0; n < 2; ++n) {
                const int row = wc * 32 + n * 16 + l15;
                bf[n] = *(const s16x8*)&lds[buf][1][row][(g ^ (row & 7)) * 8];
            }
            #pragma unroll
            for (int m = 0; m < 4; ++m)
                #pragma unroll
                for (int n = 0; n < 2; ++n)
                    acc[m][n] = __builtin_amdgcn_mfma_f32_16x16x32_bf16(
                        af[m], bf[n], acc[m][n], 0, 0, 0);
        }
    };
    STAGE_LOAD(A, 0) STAGE_LOAD(B, BK) STAGE_WRITE(A, 0)
    __syncthreads();
    #pragma unroll
    for (int s = 0; s < NSTEP; s += 2) {
        if (s + 2 < NSTEP) { STAGE_LOAD(A, (long)(s + 2) * BK) }
        compute(0);
        STAGE_WRITE(B, 1)
        __syncthreads();
        if (s + 3 < NSTEP) { STAGE_LOAD(B, (long)(s + 3) * BK) }
        compute(1);
        if (s + 2 < NSTEP) { STAGE_WRITE(A, 0) }
        __syncthreads();
    }
    const float scale = kern[0] * (1.0f / 512.0f);
    #pragma unroll
    for (int m = 0; m < 4; ++m) {
        const int row = wr * 64 + m * 16 + l4 * 4;
        #pragma unroll
        for (int n = 0; n < 2; ++n) {
            const int col = wc * 32 + n * 16 + l15;
            #pragma unroll
            for (int r = 0; r < 4; ++r)
                atomicAdd(out + (size_t)(row + r) * M_DIM + col,
                          acc[m][n][r] * scale);
        }
    }
    #undef STAGE_LOAD
    #undef STAGE_WRITE
}

__global__ __launch_bounds__(256) void init_k(float* __restrict__ out) {
    out[blockIdx.x * 256 + threadIdx.x] = 0.1f;
}

extern "C" void kernel_launch(void* const* d_in, const int* in_sizes, int n_in,
                              void* d_out, int out_size, void* d_ws, size_t ws_size,
                              hipStream_t stream) {
    const float* x    = (const float*)d_in[0];
    const float* y    = (const float*)d_in[1];
    const float* kern = (const float*)d_in[2];
    float* out = (float*)d_out;

    const size_t need = WS_PART_BYTES + 64;   // partials + counter slot
    if (ws_size >= need && d_ws != nullptr) {
        unsigned short* ws = (unsigned short*)d_ws;
        unsigned int* counter = (unsigned int*)((char*)d_ws + WS_PART_BYTES);
        hipMemsetAsync(counter, 0, sizeof(unsigned int), stream);
        gemm_fused<<<NSPLIT, THREADS, 0, stream>>>(x, y, kern, ws, counter, out);
    } else {
        init_k<<<OUT_N / 256, 256, 0, stream>>>(out);
        gemm_atomic<<<NSPLIT, THREADS, 0, stream>>>(x, y, kern, out);
    }
}

// Round 5
// 50.120 us; speedup vs baseline: 2.7538x; 2.7538x over previous
//
#include <hip/hip_runtime.h>
#include <hip/hip_bf16.h>

typedef short s16x8 __attribute__((ext_vector_type(8)));
typedef float f32x4 __attribute__((ext_vector_type(4)));

#define M_DIM   128
#define K_DIM   131072           // C*W*H = 512*16*16
#define NSPLIT  256              // split-K blocks -> 1 block/CU
#define KC      (K_DIM / NSPLIT) // 512 per block
#define BK      64               // K per LDS step
#define NSTEP   (KC / BK)        // 8
#define THREADS 512
#define OUT_N   (M_DIM * M_DIM)  // 16384
#define WS_U32_PER_BLK 8192      // 16 u32 per thread (packed bf16 pairs)
#define WS_PART_BYTES ((size_t)NSPLIT * WS_U32_PER_BLK * 4)   // 8 MiB

__device__ __forceinline__ unsigned short f2bf(float f) {
    unsigned u = __builtin_bit_cast(unsigned, f);
    u += 0x7fffu + ((u >> 16) & 1u);   // round-to-nearest-even
    return (unsigned short)(u >> 16);
}
__device__ __forceinline__ float bf2f(unsigned short h) {
    unsigned u = ((unsigned)h) << 16;
    return __builtin_bit_cast(float, u);
}
__device__ __forceinline__ s16x8 cvt8(float4 a, float4 b) {
    s16x8 r;
    r[0] = (short)f2bf(a.x); r[1] = (short)f2bf(a.y);
    r[2] = (short)f2bf(a.z); r[3] = (short)f2bf(a.w);
    r[4] = (short)f2bf(b.x); r[5] = (short)f2bf(b.y);
    r[6] = (short)f2bf(b.z); r[7] = (short)f2bf(b.w);
    return r;
}

// Fused split-K GEMM + grid barrier + reduction. All cross-block data moves
// through agent-scope atomics (coherence-point read/write) -> ZERO cache
// maintenance ops (R4's 138us regression was per-wave wbl2 + per-poll inv).
__global__ __launch_bounds__(THREADS) void gemm_fused(
    const float* __restrict__ x, const float* __restrict__ y,
    const float* __restrict__ kern,
    unsigned int* __restrict__ ws32, unsigned int* __restrict__ counter,
    float* __restrict__ out)
{
    __shared__ __align__(16) short lds[2][2][M_DIM][BK];   // 64 KiB

    const int t    = threadIdx.x;
    const long kb0 = (long)blockIdx.x * KC;

    const int srow = t >> 3;
    const int sg   = t & 7;
    const int wofs = (sg ^ (srow & 7)) * 8;   // swizzle ((srow+64)&7 == srow&7)

    const float* xa = x + (size_t)srow        * K_DIM + kb0 + sg * 8;
    const float* xb = x + (size_t)(srow + 64) * K_DIM + kb0 + sg * 8;
    const float* ya = y + (size_t)srow        * K_DIM + kb0 + sg * 8;
    const float* yb = y + (size_t)(srow + 64) * K_DIM + kb0 + sg * 8;

    const int wave = t >> 6;
    const int lane = t & 63;
    const int wr   = wave >> 2;
    const int wc   = wave & 3;
    const int l15  = lane & 15;
    const int l4   = lane >> 4;

    f32x4 acc[4][2] = {};
    float4 A0,A1,A2,A3,A4,A5,A6,A7;
    float4 B0,B1,B2,B3,B4,B5,B6,B7;

    #define STAGE_LOAD(R, kb)                                            \
        R##0 = *(const float4*)(xa + (kb)); R##1 = *(const float4*)(xa + (kb) + 4); \
        R##2 = *(const float4*)(xb + (kb)); R##3 = *(const float4*)(xb + (kb) + 4); \
        R##4 = *(const float4*)(ya + (kb)); R##5 = *(const float4*)(ya + (kb) + 4); \
        R##6 = *(const float4*)(yb + (kb)); R##7 = *(const float4*)(yb + (kb) + 4);

    #define STAGE_WRITE(R, buf)                                          \
        *(s16x8*)&lds[buf][0][srow     ][wofs] = cvt8(R##0, R##1);       \
        *(s16x8*)&lds[buf][0][srow + 64][wofs] = cvt8(R##2, R##3);       \
        *(s16x8*)&lds[buf][1][srow     ][wofs] = cvt8(R##4, R##5);       \
        *(s16x8*)&lds[buf][1][srow + 64][wofs] = cvt8(R##6, R##7);

    auto compute = [&](int buf) {
        #pragma unroll
        for (int ks = 0; ks < 2; ++ks) {
            s16x8 af[4], bf[2];
            const int g = ks * 4 + l4;
            #pragma unroll
            for (int m = 0; m < 4; ++m) {
                const int row = wr * 64 + m * 16 + l15;
                af[m] = *(const s16x8*)&lds[buf][0][row][(g ^ (row & 7)) * 8];
            }
            #pragma unroll
            for (int n = 0; n < 2; ++n) {
                const int row = wc * 32 + n * 16 + l15;
                bf[n] = *(const s16x8*)&lds[buf][1][row][(g ^ (row & 7)) * 8];
            }
            #pragma unroll
            for (int m = 0; m < 4; ++m)
                #pragma unroll
                for (int n = 0; n < 2; ++n)
                    acc[m][n] = __builtin_amdgcn_mfma_f32_16x16x32_bf16(
                        af[m], bf[n], acc[m][n], 0, 0, 0);
        }
    };

    STAGE_LOAD(A, 0)
    STAGE_LOAD(B, BK)
    STAGE_WRITE(A, 0)
    __syncthreads();

    #pragma unroll
    for (int s = 0; s < NSTEP; s += 2) {
        if (s + 2 < NSTEP) { STAGE_LOAD(A, (long)(s + 2) * BK) }
        compute(0);
        STAGE_WRITE(B, 1)
        __syncthreads();
        if (s + 3 < NSTEP) { STAGE_LOAD(B, (long)(s + 3) * BK) }
        compute(1);
        if (s + 2 < NSTEP) { STAGE_WRITE(A, 0) }
        __syncthreads();
    }

    // ---- partial store, fragment-native layout: ws32[blk][i*512 + t],
    // i = m*4 + n*2 + rp packs (acc[m][n][rp*2], acc[m][n][rp*2+1]) lo|hi.
    // Agent-scope relaxed atomic stores: write-through to coherence point,
    // perfectly coalesced (lane-consecutive u32).
    {
        unsigned int* wp = ws32 + (size_t)blockIdx.x * WS_U32_PER_BLK;
        #pragma unroll
        for (int m = 0; m < 4; ++m)
            #pragma unroll
            for (int n = 0; n < 2; ++n)
                #pragma unroll
                for (int rp = 0; rp < 2; ++rp) {
                    const int i = m * 4 + n * 2 + rp;
                    unsigned v = (unsigned)f2bf(acc[m][n][rp * 2]) |
                                 ((unsigned)f2bf(acc[m][n][rp * 2 + 1]) << 16);
                    __hip_atomic_store(wp + i * 512 + t, v,
                                       __ATOMIC_RELAXED, __HIP_MEMORY_SCOPE_AGENT);
                }
    }

    // ---- grid barrier: syncthreads drains every wave's stores (vmcnt 0);
    // thread-0 RELEASE add (one wbl2 per BLOCK); RELAXED polls (no cache ops).
    __syncthreads();
    if (t == 0) {
        __hip_atomic_fetch_add(counter, 1u, __ATOMIC_RELEASE,
                               __HIP_MEMORY_SCOPE_AGENT);
        while (__hip_atomic_load(counter, __ATOMIC_RELAXED,
                                 __HIP_MEMORY_SCOPE_AGENT) < NSPLIT)
            __builtin_amdgcn_s_sleep(16);
        (void)__hip_atomic_load(counter, __ATOMIC_ACQUIRE,
                                __HIP_MEMORY_SCOPE_AGENT);
    }
    __syncthreads();

    // ---- phase 2: block b reduces u32 lanes [b*32, b*32+32) over 256 splits
    // via agent-scope atomic loads (coherence-point reads; no stale caches).
    {
        float* red = (float*)lds;          // [sc][32][2] floats = 4 KiB
        const int b  = blockIdx.x;
        const int qo = t & 31;             // u32-lane offset within block's 32
        const int sc = t >> 5;             // 16 split-chunks of 16 splits
        const unsigned int* rp = ws32 + (size_t)(sc * 16) * WS_U32_PER_BLK
                                      + b * 32 + qo;
        float alo = 0.f, ahi = 0.f;
        #pragma unroll
        for (int j = 0; j < 16; ++j) {
            unsigned v = __hip_atomic_load(rp + (size_t)j * WS_U32_PER_BLK,
                                           __ATOMIC_RELAXED,
                                           __HIP_MEMORY_SCOPE_AGENT);
            alo += bf2f((unsigned short)(v & 0xffff));
            ahi += bf2f((unsigned short)(v >> 16));
        }
        red[(sc * 32 + qo) * 2 + 0] = alo;
        red[(sc * 32 + qo) * 2 + 1] = ahi;
        __syncthreads();
        for (int off = 8; off > 0; off >>= 1) {
            if (sc < off) {
                red[(sc * 32 + qo) * 2 + 0] += red[((sc + off) * 32 + qo) * 2 + 0];
                red[(sc * 32 + qo) * 2 + 1] += red[((sc + off) * 32 + qo) * 2 + 1];
            }
            __syncthreads();
        }
        if (t < 64) {
            // q_lin = b*32 + (t>>1); half = t&1. Decode i, gemm-thread:
            const int q_lin = b * 32 + (t >> 1);
            const int half  = t & 1;
            const int i_    = q_lin >> 9;          // 0..15
            const int tg    = q_lin & 511;
            const int m_    = i_ >> 2;
            const int n_    = (i_ >> 1) & 1;
            const int rp_   = i_ & 1;
            const int wv    = tg >> 6, ln = tg & 63;
            const int row   = (wv >> 2) * 64 + m_ * 16 + (ln >> 4) * 4 + rp_ * 2 + half;
            const int col   = (wv & 3) * 32 + n_ * 16 + (ln & 15);
            const float scale = kern[0] * (1.0f / 512.0f);
            out[row * M_DIM + col] = red[t] * scale + 0.1f;
        }
    }
    #undef STAGE_LOAD
    #undef STAGE_WRITE
}

// ---------------- fallback (ws too small): init + atomic gemm
__global__ __launch_bounds__(THREADS) void gemm_atomic(
    const float* __restrict__ x, const float* __restrict__ y,
    const float* __restrict__ kern, float* __restrict__ out)
{
    __shared__ __align__(16) short lds[2][2][M_DIM][BK];
    const int t    = threadIdx.x;
    const long kb0 = (long)blockIdx.x * KC;
    const int srow = t >> 3, sg = t & 7;
    const int wofs = (sg ^ (srow & 7)) * 8;
    const float* xa = x + (size_t)srow        * K_DIM + kb0 + sg * 8;
    const float* xb = x + (size_t)(srow + 64) * K_DIM + kb0 + sg * 8;
    const float* ya = y + (size_t)srow        * K_DIM + kb0 + sg * 8;
    const float* yb = y + (size_t)(srow + 64) * K_DIM + kb0 + sg * 8;
    const int wave = t >> 6, lane = t & 63;
    const int wr = wave >> 2, wc = wave & 3, l15 = lane & 15, l4 = lane >> 4;
    f32x4 acc[4][2] = {};
    float4 A0,A1,A2,A3,A4,A5,A6,A7, B0,B1,B2,B3,B4,B5,B6,B7;
    #define STAGE_LOAD(R, kb)                                            \
        R##0 = *(const float4*)(xa + (kb)); R##1 = *(const float4*)(xa + (kb) + 4); \
        R##2 = *(const float4*)(xb + (kb)); R##3 = *(const float4*)(xb + (kb) + 4); \
        R##4 = *(const float4*)(ya + (kb)); R##5 = *(const float4*)(ya + (kb) + 4); \
        R##6 = *(const float4*)(yb + (kb)); R##7 = *(const float4*)(yb + (kb) + 4);
    #define STAGE_WRITE(R, buf)                                          \
        *(s16x8*)&lds[buf][0][srow     ][wofs] = cvt8(R##0, R##1);       \
        *(s16x8*)&lds[buf][0][srow + 64][wofs] = cvt8(R##2, R##3);       \
        *(s16x8*)&lds[buf][1][srow     ][wofs] = cvt8(R##4, R##5);       \
        *(s16x8*)&lds[buf][1][srow + 64][wofs] = cvt8(R##6, R##7);
    auto compute = [&](int buf) {
        #pragma unroll
        for (int ks = 0; ks < 2; ++ks) {
            s16x8 af[4], bf[2];
            const int g = ks * 4 + l4;
            #pragma unroll
            for (int m = 0; m < 4; ++m) {
                const int row = wr * 64 + m * 16 + l15;
                af[m] = *(const s16x8*)&lds[buf][0][row][(g ^ (row & 7)) * 8];
            }
            #pragma unroll
            for (int n = 0; n < 2; ++n) {
                const int row = wc * 32 + n * 16 + l15;
                bf[n] = *(const s16x8*)&lds[buf][1][row][(g ^ (row & 7)) * 8];
            }
            #pragma unroll
            for (int m = 0; m < 4; ++m)
                #pragma unroll
                for (int n = 0; n < 2; ++n)
                    acc[m][n] = __builtin_amdgcn_mfma_f32_16x16x32_bf16(
                        af[m], bf[n], acc[m][n], 0, 0, 0);
        }
    };
    STAGE_LOAD(A, 0) STAGE_LOAD(B, BK) STAGE_WRITE(A, 0)
    __syncthreads();
    #pragma unroll
    for (int s = 0; s < NSTEP; s += 2) {
        if (s + 2 < NSTEP) { STAGE_LOAD(A, (long)(s + 2) * BK) }
        compute(0);
        STAGE_WRITE(B, 1)
        __syncthreads();
        if (s + 3 < NSTEP) { STAGE_LOAD(B, (long)(s + 3) * BK) }
        compute(1);
        if (s + 2 < NSTEP) { STAGE_WRITE(A, 0) }
        __syncthreads();
    }
    const float scale = kern[0] * (1.0f / 512.0f);
    #pragma unroll
    for (int m = 0; m < 4; ++m) {
        const int row = wr * 64 + m * 16 + l4 * 4;
        #pragma unroll
        for (int n = 0; n < 2; ++n) {
            const int col = wc * 32 + n * 16 + l15;
            #pragma unroll
            for (int r = 0; r < 4; ++r)
                atomicAdd(out + (size_t)(row + r) * M_DIM + col,
                          acc[m][n][r] * scale);
        }
    }
    #undef STAGE_LOAD
    #undef STAGE_WRITE
}

__global__ __launch_bounds__(256) void init_k(float* __restrict__ out) {
    out[blockIdx.x * 256 + threadIdx.x] = 0.1f;
}

extern "C" void kernel_launch(void* const* d_in, const int* in_sizes, int n_in,
                              void* d_out, int out_size, void* d_ws, size_t ws_size,
                              hipStream_t stream) {
    const float* x    = (const float*)d_in[0];
    const float* y    = (const float*)d_in[1];
    const float* kern = (const float*)d_in[2];
    float* out = (float*)d_out;

    const size_t need = WS_PART_BYTES + 64;   // partials + counter slot
    if (ws_size >= need && d_ws != nullptr) {
        unsigned int* ws32 = (unsigned int*)d_ws;
        unsigned int* counter = (unsigned int*)((char*)d_ws + WS_PART_BYTES);
        hipMemsetAsync(counter, 0, sizeof(unsigned int), stream);
        gemm_fused<<<NSPLIT, THREADS, 0, stream>>>(x, y, kern, ws32, counter, out);
    } else {
        init_k<<<OUT_N / 256, 256, 0, stream>>>(out);
        gemm_atomic<<<NSPLIT, THREADS, 0, stream>>>(x, y, kern, out);
    }
}

// Round 6
// 41.865 us; speedup vs baseline: 3.2968x; 1.1972x over previous
//
#include <hip/hip_runtime.h>
#include <hip/hip_bf16.h>

typedef short s16x8 __attribute__((ext_vector_type(8)));
typedef float f32x4 __attribute__((ext_vector_type(4)));

#define M_DIM   128
#define K_DIM   131072           // C*W*H = 512*16*16
#define NSPLIT  256              // split-K blocks -> 1 block/CU
#define KC      (K_DIM / NSPLIT) // 512 per block
#define BK      64               // K per LDS step
#define NSTEP   (KC / BK)        // 8
#define THREADS 512
#define OUT_N   (M_DIM * M_DIM)  // 16384
#define WS_U32_PER_BLK 8192      // 16 u32 per thread (packed bf16 pairs)
#define WS_PART_BYTES ((size_t)NSPLIT * WS_U32_PER_BLK * 4)   // 8 MiB

__device__ __forceinline__ unsigned short f2bf(float f) {
    unsigned u = __builtin_bit_cast(unsigned, f);
    u += 0x7fffu + ((u >> 16) & 1u);   // round-to-nearest-even
    return (unsigned short)(u >> 16);
}
__device__ __forceinline__ float bf2f(unsigned short h) {
    unsigned u = ((unsigned)h) << 16;
    return __builtin_bit_cast(float, u);
}
__device__ __forceinline__ s16x8 cvt8(float4 a, float4 b) {
    s16x8 r;
    r[0] = (short)f2bf(a.x); r[1] = (short)f2bf(a.y);
    r[2] = (short)f2bf(a.z); r[3] = (short)f2bf(a.w);
    r[4] = (short)f2bf(b.x); r[5] = (short)f2bf(b.y);
    r[6] = (short)f2bf(b.z); r[7] = (short)f2bf(b.w);
    return r;
}

// Fused split-K GEMM + grid barrier + reduction.
// ZERO cache-maintenance ops anywhere:
//  - R4 failed (138us): per-wave wbl2 + per-poll L2-invalidate.
//  - R5 failed (50us):  256x RELEASE fetch_add -> 256 full-L2 wbl2 walks
//    stalling concurrent gemm streams, + 256x ACQUIRE inv at barrier exit.
//  - R6: partial stores are agent-scope RELAXED write-through atomics;
//    __syncthreads drains store acks (vmcnt 0) so a RELAXED counter add
//    suffices; phase-2 RELAXED agent loads read the coherence point.
__global__ __launch_bounds__(THREADS) void gemm_fused(
    const float* __restrict__ x, const float* __restrict__ y,
    const float* __restrict__ kern,
    unsigned int* __restrict__ ws32, unsigned int* __restrict__ counter,
    float* __restrict__ out)
{
    __shared__ __align__(16) short lds[2][2][M_DIM][BK];   // 64 KiB

    const int t    = threadIdx.x;
    const long kb0 = (long)blockIdx.x * KC;

    const int srow = t >> 3;
    const int sg   = t & 7;
    const int wofs = (sg ^ (srow & 7)) * 8;   // swizzle ((srow+64)&7 == srow&7)

    const float* xa = x + (size_t)srow        * K_DIM + kb0 + sg * 8;
    const float* xb = x + (size_t)(srow + 64) * K_DIM + kb0 + sg * 8;
    const float* ya = y + (size_t)srow        * K_DIM + kb0 + sg * 8;
    const float* yb = y + (size_t)(srow + 64) * K_DIM + kb0 + sg * 8;

    const int wave = t >> 6;
    const int lane = t & 63;
    const int wr   = wave >> 2;
    const int wc   = wave & 3;
    const int l15  = lane & 15;
    const int l4   = lane >> 4;

    f32x4 acc[4][2] = {};
    float4 A0,A1,A2,A3,A4,A5,A6,A7;
    float4 B0,B1,B2,B3,B4,B5,B6,B7;

    #define STAGE_LOAD(R, kb)                                            \
        R##0 = *(const float4*)(xa + (kb)); R##1 = *(const float4*)(xa + (kb) + 4); \
        R##2 = *(const float4*)(xb + (kb)); R##3 = *(const float4*)(xb + (kb) + 4); \
        R##4 = *(const float4*)(ya + (kb)); R##5 = *(const float4*)(ya + (kb) + 4); \
        R##6 = *(const float4*)(yb + (kb)); R##7 = *(const float4*)(yb + (kb) + 4);

    #define STAGE_WRITE(R, buf)                                          \
        *(s16x8*)&lds[buf][0][srow     ][wofs] = cvt8(R##0, R##1);       \
        *(s16x8*)&lds[buf][0][srow + 64][wofs] = cvt8(R##2, R##3);       \
        *(s16x8*)&lds[buf][1][srow     ][wofs] = cvt8(R##4, R##5);       \
        *(s16x8*)&lds[buf][1][srow + 64][wofs] = cvt8(R##6, R##7);

    auto compute = [&](int buf) {
        #pragma unroll
        for (int ks = 0; ks < 2; ++ks) {
            s16x8 af[4], bf[2];
            const int g = ks * 4 + l4;
            #pragma unroll
            for (int m = 0; m < 4; ++m) {
                const int row = wr * 64 + m * 16 + l15;
                af[m] = *(const s16x8*)&lds[buf][0][row][(g ^ (row & 7)) * 8];
            }
            #pragma unroll
            for (int n = 0; n < 2; ++n) {
                const int row = wc * 32 + n * 16 + l15;
                bf[n] = *(const s16x8*)&lds[buf][1][row][(g ^ (row & 7)) * 8];
            }
            #pragma unroll
            for (int m = 0; m < 4; ++m)
                #pragma unroll
                for (int n = 0; n < 2; ++n)
                    acc[m][n] = __builtin_amdgcn_mfma_f32_16x16x32_bf16(
                        af[m], bf[n], acc[m][n], 0, 0, 0);
        }
    };

    STAGE_LOAD(A, 0)
    STAGE_LOAD(B, BK)
    STAGE_WRITE(A, 0)
    __syncthreads();

    #pragma unroll
    for (int s = 0; s < NSTEP; s += 2) {
        if (s + 2 < NSTEP) { STAGE_LOAD(A, (long)(s + 2) * BK) }
        compute(0);
        STAGE_WRITE(B, 1)
        __syncthreads();
        if (s + 3 < NSTEP) { STAGE_LOAD(B, (long)(s + 3) * BK) }
        compute(1);
        if (s + 2 < NSTEP) { STAGE_WRITE(A, 0) }
        __syncthreads();
    }

    // ---- partial store, fragment-native layout: ws32[blk][i*512 + t],
    // i = m*4 + n*2 + rp packs (acc[m][n][rp*2], acc[m][n][rp*2+1]) lo|hi.
    // RELAXED agent atomics: write-through to coherence point, coalesced.
    {
        unsigned int* wp = ws32 + (size_t)blockIdx.x * WS_U32_PER_BLK;
        #pragma unroll
        for (int m = 0; m < 4; ++m)
            #pragma unroll
            for (int n = 0; n < 2; ++n)
                #pragma unroll
                for (int rp = 0; rp < 2; ++rp) {
                    const int i = m * 4 + n * 2 + rp;
                    unsigned v = (unsigned)f2bf(acc[m][n][rp * 2]) |
                                 ((unsigned)f2bf(acc[m][n][rp * 2 + 1]) << 16);
                    __hip_atomic_store(wp + i * 512 + t, v,
                                       __ATOMIC_RELAXED, __HIP_MEMORY_SCOPE_AGENT);
                }
    }

    // ---- grid barrier. __syncthreads emits s_waitcnt vmcnt(0): the write-
    // through stores are acked at the coherence point before the add issues,
    // so RELAXED is sufficient -> plain global_atomic_add, NO wbl2/inv ever.
    __syncthreads();
    if (t == 0) {
        __hip_atomic_fetch_add(counter, 1u, __ATOMIC_RELAXED,
                               __HIP_MEMORY_SCOPE_AGENT);
        while (__hip_atomic_load(counter, __ATOMIC_RELAXED,
                                 __HIP_MEMORY_SCOPE_AGENT) < NSPLIT)
            __builtin_amdgcn_s_sleep(16);
    }
    __syncthreads();

    // ---- phase 2: block b reduces u32 lanes [b*32, b*32+32) over 256 splits
    // via RELAXED agent loads (coherence-point reads; stale caches bypassed).
    {
        float* red = (float*)lds;          // [sc][32][2] floats = 4 KiB
        const int b  = blockIdx.x;
        const int qo = t & 31;             // u32-lane offset within block's 32
        const int sc = t >> 5;             // 16 split-chunks of 16 splits
        const unsigned int* rp = ws32 + (size_t)(sc * 16) * WS_U32_PER_BLK
                                      + b * 32 + qo;
        float alo = 0.f, ahi = 0.f;
        #pragma unroll
        for (int j = 0; j < 16; ++j) {
            unsigned v = __hip_atomic_load(rp + (size_t)j * WS_U32_PER_BLK,
                                           __ATOMIC_RELAXED,
                                           __HIP_MEMORY_SCOPE_AGENT);
            alo += bf2f((unsigned short)(v & 0xffff));
            ahi += bf2f((unsigned short)(v >> 16));
        }
        red[(sc * 32 + qo) * 2 + 0] = alo;
        red[(sc * 32 + qo) * 2 + 1] = ahi;
        __syncthreads();
        for (int off = 8; off > 0; off >>= 1) {
            if (sc < off) {
                red[(sc * 32 + qo) * 2 + 0] += red[((sc + off) * 32 + qo) * 2 + 0];
                red[(sc * 32 + qo) * 2 + 1] += red[((sc + off) * 32 + qo) * 2 + 1];
            }
            __syncthreads();
        }
        if (t < 64) {
            // q_lin = b*32 + (t>>1); half = t&1. Decode i, gemm-thread:
            const int q_lin = b * 32 + (t >> 1);
            const int half  = t & 1;
            const int i_    = q_lin >> 9;          // 0..15
            const int tg    = q_lin & 511;
            const int m_    = i_ >> 2;
            const int n_    = (i_ >> 1) & 1;
            const int rp_   = i_ & 1;
            const int wv    = tg >> 6, ln = tg & 63;
            const int row   = (wv >> 2) * 64 + m_ * 16 + (ln >> 4) * 4 + rp_ * 2 + half;
            const int col   = (wv & 3) * 32 + n_ * 16 + (ln & 15);
            const float scale = kern[0] * (1.0f / 512.0f);
            out[row * M_DIM + col] = red[t] * scale + 0.1f;
        }
    }
    #undef STAGE_LOAD
    #undef STAGE_WRITE
}

// ---------------- fallback (ws too small): init + atomic gemm
__global__ __launch_bounds__(THREADS) void gemm_atomic(
    const float* __restrict__ x, const float* __restrict__ y,
    const float* __restrict__ kern, float* __restrict__ out)
{
    __shared__ __align__(16) short lds[2][2][M_DIM][BK];
    const int t    = threadIdx.x;
    const long kb0 = (long)blockIdx.x * KC;
    const int srow = t >> 3, sg = t & 7;
    const int wofs = (sg ^ (srow & 7)) * 8;
    const float* xa = x + (size_t)srow        * K_DIM + kb0 + sg * 8;
    const float* xb = x + (size_t)(srow + 64) * K_DIM + kb0 + sg * 8;
    const float* ya = y + (size_t)srow        * K_DIM + kb0 + sg * 8;
    const float* yb = y + (size_t)(srow + 64) * K_DIM + kb0 + sg * 8;
    const int wave = t >> 6, lane = t & 63;
    const int wr = wave >> 2, wc = wave & 3, l15 = lane & 15, l4 = lane >> 4;
    f32x4 acc[4][2] = {};
    float4 A0,A1,A2,A3,A4,A5,A6,A7, B0,B1,B2,B3,B4,B5,B6,B7;
    #define STAGE_LOAD(R, kb)                                            \
        R##0 = *(const float4*)(xa + (kb)); R##1 = *(const float4*)(xa + (kb) + 4); \
        R##2 = *(const float4*)(xb + (kb)); R##3 = *(const float4*)(xb + (kb) + 4); \
        R##4 = *(const float4*)(ya + (kb)); R##5 = *(const float4*)(ya + (kb) + 4); \
        R##6 = *(const float4*)(yb + (kb)); R##7 = *(const float4*)(yb + (kb) + 4);
    #define STAGE_WRITE(R, buf)                                          \
        *(s16x8*)&lds[buf][0][srow     ][wofs] = cvt8(R##0, R##1);       \
        *(s16x8*)&lds[buf][0][srow + 64][wofs] = cvt8(R##2, R##3);       \
        *(s16x8*)&lds[buf][1][srow     ][wofs] = cvt8(R##4, R##5);       \
        *(s16x8*)&lds[buf][1][srow + 64][wofs] = cvt8(R##6, R##7);
    auto compute = [&](int buf) {
        #pragma unroll
        for (int ks = 0; ks < 2; ++ks) {
            s16x8 af[4], bf[2];
            const int g = ks * 4 + l4;
            #pragma unroll
            for (int m = 0; m < 4; ++m) {
                const int row = wr * 64 + m * 16 + l15;
                af[m] = *(const s16x8*)&lds[buf][0][row][(g ^ (row & 7)) * 8];
            }
            #pragma unroll
            for (int n = 0; n < 2; ++n) {
                const int row = wc * 32 + n * 16 + l15;
                bf[n] = *(const s16x8*)&lds[buf][1][row][(g ^ (row & 7)) * 8];
            }
            #pragma unroll
            for (int m = 0; m < 4; ++m)
                #pragma unroll
                for (int n = 0; n < 2; ++n)
                    acc[m][n] = __builtin_amdgcn_mfma_f32_16x16x32_bf16(
                        af[m], bf[n], acc[m][n], 0, 0, 0);
        }
    };
    STAGE_LOAD(A, 0) STAGE_LOAD(B, BK) STAGE_WRITE(A, 0)
    __syncthreads();
    #pragma unroll
    for (int s = 0; s < NSTEP; s += 2) {
        if (s + 2 < NSTEP) { STAGE_LOAD(A, (long)(s + 2) * BK) }
        compute(0);
        STAGE_WRITE(B, 1)
        __syncthreads();
        if (s + 3 < NSTEP) { STAGE_LOAD(B, (long)(s + 3) * BK) }
        compute(1);
        if (s + 2 < NSTEP) { STAGE_WRITE(A, 0) }
        __syncthreads();
    }
    const float scale = kern[0] * (1.0f / 512.0f);
    #pragma unroll
    for (int m = 0; m < 4; ++m) {
        const int row = wr * 64 + m * 16 + l4 * 4;
        #pragma unroll
        for (int n = 0; n < 2; ++n) {
            const int col = wc * 32 + n * 16 + l15;
            #pragma unroll
            for (int r = 0; r < 4; ++r)
                atomicAdd(out + (size_t)(row + r) * M_DIM + col,
                          acc[m][n][r] * scale);
        }
    }
    #undef STAGE_LOAD
    #undef STAGE_WRITE
}

__global__ __launch_bounds__(256) void init_k(float* __restrict__ out) {
    out[blockIdx.x * 256 + threadIdx.x] = 0.1f;
}

extern "C" void kernel_launch(void* const* d_in, const int* in_sizes, int n_in,
                              void* d_out, int out_size, void* d_ws, size_t ws_size,
                              hipStream_t stream) {
    const float* x    = (const float*)d_in[0];
    const float* y    = (const float*)d_in[1];
    const float* kern = (const float*)d_in[2];
    float* out = (float*)d_out;

    const size_t need = WS_PART_BYTES + 64;   // partials + counter slot
    if (ws_size >= need && d_ws != nullptr) {
        unsigned int* ws32 = (unsigned int*)d_ws;
        unsigned int* counter = (unsigned int*)((char*)d_ws + WS_PART_BYTES);
        hipMemsetAsync(counter, 0, sizeof(unsigned int), stream);
        gemm_fused<<<NSPLIT, THREADS, 0, stream>>>(x, y, kern, ws32, counter, out);
    } else {
        init_k<<<OUT_N / 256, 256, 0, stream>>>(out);
        gemm_atomic<<<NSPLIT, THREADS, 0, stream>>>(x, y, kern, out);
    }
}

// Round 7
// 32.959 us; speedup vs baseline: 4.1876x; 1.2702x over previous
//
#include <hip/hip_runtime.h>
#include <hip/hip_bf16.h>

typedef short s16x8 __attribute__((ext_vector_type(8)));
typedef float f32x4 __attribute__((ext_vector_type(4)));

#define M_DIM   128
#define K_DIM   131072           // C*W*H = 512*16*16
#define NSPLIT  512              // split-K blocks -> 2 blocks/CU
#define KC      (K_DIM / NSPLIT) // 256 per block
#define BK      64               // K per LDS step
#define NSTEP   (KC / BK)        // 4
#define THREADS 512
#define OUT_N   (M_DIM * M_DIM)  // 16384

__device__ __forceinline__ unsigned short f2bf(float f) {
    unsigned u = __builtin_bit_cast(unsigned, f);
    u += 0x7fffu + ((u >> 16) & 1u);   // round-to-nearest-even
    return (unsigned short)(u >> 16);
}
__device__ __forceinline__ float bf2f(unsigned short h) {
    unsigned u = ((unsigned)h) << 16;
    return __builtin_bit_cast(float, u);
}
__device__ __forceinline__ s16x8 cvt8(float4 a, float4 b) {
    s16x8 r;
    r[0] = (short)f2bf(a.x); r[1] = (short)f2bf(a.y);
    r[2] = (short)f2bf(a.z); r[3] = (short)f2bf(a.w);
    r[4] = (short)f2bf(b.x); r[5] = (short)f2bf(b.y);
    r[6] = (short)f2bf(b.z); r[7] = (short)f2bf(b.w);
    return r;
}

// Split-K GEMM: block b computes partial[i][j] = sum_{k in chunk b} x[i,k]*y[j,k].
// 2 blocks/CU (barrier stalls of one block covered by the other) + depth-2
// register prefetch (stage_write waits only on loads issued a full iter ago).
__global__ __launch_bounds__(THREADS) void gemm_splitk(
    const float* __restrict__ x, const float* __restrict__ y,
    const float* __restrict__ kern,
    unsigned short* __restrict__ ws, float* __restrict__ out, int use_ws)
{
    __shared__ __align__(16) short lds[2][2][M_DIM][BK];   // 64 KiB

    const int t    = threadIdx.x;
    const long kb0 = (long)blockIdx.x * KC;

    // staging: thread t handles rows (t>>3), (t>>3)+64; 8-float group t&7
    const int srow = t >> 3;
    const int sg   = t & 7;
    const int wofs = (sg ^ (srow & 7)) * 8;   // swizzle ((srow+64)&7 == srow&7)

    const float* xa = x + (size_t)srow        * K_DIM + kb0 + sg * 8;
    const float* xb = x + (size_t)(srow + 64) * K_DIM + kb0 + sg * 8;
    const float* ya = y + (size_t)srow        * K_DIM + kb0 + sg * 8;
    const float* yb = y + (size_t)(srow + 64) * K_DIM + kb0 + sg * 8;

    // wave tile: 8 waves 2(row)x4(col); each wave 64x32 = 4x2 frags of 16x16
    const int wave = t >> 6;
    const int lane = t & 63;
    const int wr   = wave >> 2;
    const int wc   = wave & 3;
    const int l15  = lane & 15;
    const int l4   = lane >> 4;

    f32x4 acc[4][2] = {};
    float4 A0,A1,A2,A3,A4,A5,A6,A7;
    float4 B0,B1,B2,B3,B4,B5,B6,B7;

    #define STAGE_LOAD(R, kb)                                            \
        R##0 = *(const float4*)(xa + (kb)); R##1 = *(const float4*)(xa + (kb) + 4); \
        R##2 = *(const float4*)(xb + (kb)); R##3 = *(const float4*)(xb + (kb) + 4); \
        R##4 = *(const float4*)(ya + (kb)); R##5 = *(const float4*)(ya + (kb) + 4); \
        R##6 = *(const float4*)(yb + (kb)); R##7 = *(const float4*)(yb + (kb) + 4);

    #define STAGE_WRITE(R, buf)                                          \
        *(s16x8*)&lds[buf][0][srow     ][wofs] = cvt8(R##0, R##1);       \
        *(s16x8*)&lds[buf][0][srow + 64][wofs] = cvt8(R##2, R##3);       \
        *(s16x8*)&lds[buf][1][srow     ][wofs] = cvt8(R##4, R##5);       \
        *(s16x8*)&lds[buf][1][srow + 64][wofs] = cvt8(R##6, R##7);

    auto compute = [&](int buf) {
        #pragma unroll
        for (int ks = 0; ks < 2; ++ks) {
            s16x8 af[4], bf[2];
            const int g = ks * 4 + l4;
            #pragma unroll
            for (int m = 0; m < 4; ++m) {
                const int row = wr * 64 + m * 16 + l15;
                af[m] = *(const s16x8*)&lds[buf][0][row][(g ^ (row & 7)) * 8];
            }
            #pragma unroll
            for (int n = 0; n < 2; ++n) {
                const int row = wc * 32 + n * 16 + l15;
                bf[n] = *(const s16x8*)&lds[buf][1][row][(g ^ (row & 7)) * 8];
            }
            #pragma unroll
            for (int m = 0; m < 4; ++m)
                #pragma unroll
                for (int n = 0; n < 2; ++n)
                    acc[m][n] = __builtin_amdgcn_mfma_f32_16x16x32_bf16(
                        af[m], bf[n], acc[m][n], 0, 0, 0);
        }
    };

    // prologue: steps 0,1 in flight; write step 0
    STAGE_LOAD(A, 0)
    STAGE_LOAD(B, BK)
    STAGE_WRITE(A, 0)
    __syncthreads();

    #pragma unroll
    for (int s = 0; s < NSTEP; s += 2) {
        if (s + 2 < NSTEP) { STAGE_LOAD(A, (long)(s + 2) * BK) }
        compute(0);
        STAGE_WRITE(B, 1)
        __syncthreads();
        if (s + 3 < NSTEP) { STAGE_LOAD(B, (long)(s + 3) * BK) }
        compute(1);
        if (s + 2 < NSTEP) { STAGE_WRITE(A, 0) }
        __syncthreads();
    }

    // epilogue: D frag mapping col=lane&15, row=(lane>>4)*4+reg
    if (use_ws) {
        unsigned short* wp = ws + (size_t)blockIdx.x * OUT_N;
        #pragma unroll
        for (int m = 0; m < 4; ++m) {
            const int row = wr * 64 + m * 16 + l4 * 4;
            #pragma unroll
            for (int n = 0; n < 2; ++n) {
                const int col = wc * 32 + n * 16 + l15;
                #pragma unroll
                for (int r = 0; r < 4; ++r)
                    wp[(size_t)(row + r) * M_DIM + col] =
                        (unsigned short)f2bf(acc[m][n][r]);
            }
        }
    } else {
        const float scale = kern[0] * (1.0f / 512.0f);
        #pragma unroll
        for (int m = 0; m < 4; ++m) {
            const int row = wr * 64 + m * 16 + l4 * 4;
            #pragma unroll
            for (int n = 0; n < 2; ++n) {
                const int col = wc * 32 + n * 16 + l15;
                #pragma unroll
                for (int r = 0; r < 4; ++r)
                    atomicAdd(out + (size_t)(row + r) * M_DIM + col,
                              acc[m][n][r] * scale);
            }
        }
    }
    #undef STAGE_LOAD
    #undef STAGE_WRITE
}

// 256 blocks x 256 threads: block b reduces 64 outputs over all 512 splits.
__global__ __launch_bounds__(256) void reduce_k(
    const unsigned short* __restrict__ ws, const float* __restrict__ kern,
    float* __restrict__ out)
{
    __shared__ float red[16][16][4];   // [s-chunk][quad][elem]
    const int b  = blockIdx.x;         // 256
    const int qi = threadIdx.x & 15;   // 16 quads of 4 outputs = 64 outputs
    const int sc = threadIdx.x >> 4;   // 16 s-chunks of 32 splits
    const int e0 = b * 64 + qi * 4;

    float a0 = 0.f, a1 = 0.f, a2 = 0.f, a3 = 0.f;
    #pragma unroll 4
    for (int s = sc * 32; s < sc * 32 + 32; ++s) {
        ushort4 v = *(const ushort4*)(ws + (size_t)s * OUT_N + e0);
        a0 += bf2f(v.x); a1 += bf2f(v.y); a2 += bf2f(v.z); a3 += bf2f(v.w);
    }
    red[sc][qi][0] = a0; red[sc][qi][1] = a1;
    red[sc][qi][2] = a2; red[sc][qi][3] = a3;
    __syncthreads();
    for (int off = 8; off > 0; off >>= 1) {
        if (sc < off) {
            #pragma unroll
            for (int r = 0; r < 4; ++r)
                red[sc][qi][r] += red[sc + off][qi][r];
        }
        __syncthreads();
    }
    if (sc == 0) {
        const float scale = kern[0] * (1.0f / 512.0f);
        float4 o;
        o.x = red[0][qi][0] * scale + 0.1f;
        o.y = red[0][qi][1] * scale + 0.1f;
        o.z = red[0][qi][2] * scale + 0.1f;
        o.w = red[0][qi][3] * scale + 0.1f;
        *(float4*)(out + e0) = o;
    }
}

__global__ __launch_bounds__(256) void init_k(float* __restrict__ out) {
    out[blockIdx.x * 256 + threadIdx.x] = 0.1f;
}

extern "C" void kernel_launch(void* const* d_in, const int* in_sizes, int n_in,
                              void* d_out, int out_size, void* d_ws, size_t ws_size,
                              hipStream_t stream) {
    const float* x    = (const float*)d_in[0];
    const float* y    = (const float*)d_in[1];
    const float* kern = (const float*)d_in[2];
    float* out = (float*)d_out;

    const size_t need = (size_t)NSPLIT * OUT_N * sizeof(unsigned short);
    if (ws_size >= need && d_ws != nullptr) {
        unsigned short* ws = (unsigned short*)d_ws;
        gemm_splitk<<<NSPLIT, THREADS, 0, stream>>>(x, y, kern, ws, out, 1);
        reduce_k<<<256, 256, 0, stream>>>(ws, kern, out);
    } else {
        init_k<<<OUT_N / 256, 256, 0, stream>>>(out);
        gemm_splitk<<<NSPLIT, THREADS, 0, stream>>>(x, y, kern, nullptr, out, 0);
    }
}

// Round 8
// 29.160 us; speedup vs baseline: 4.7331x; 1.1303x over previous
//
#include <hip/hip_runtime.h>
#include <hip/hip_bf16.h>

typedef short s16x8 __attribute__((ext_vector_type(8)));
typedef float f32x4 __attribute__((ext_vector_type(4)));

#define M_DIM   128
#define K_DIM   131072           // C*W*H = 512*16*16
#define NSPLIT  256              // split-K blocks -> 1 block/CU (optimal: R2/R7 falsified 2/CU)
#define KC      (K_DIM / NSPLIT) // 512 per block
#define BK      64               // K per LDS step
#define NSTEP   (KC / BK)        // 8
#define THREADS 512
#define OUT_N   (M_DIM * M_DIM)  // 16384
#define WS_U32_PER_BLK 8192      // 16 packed-bf16-pair u32 per thread

__device__ __forceinline__ unsigned short f2bf(float f) {
    unsigned u = __builtin_bit_cast(unsigned, f);
    u += 0x7fffu + ((u >> 16) & 1u);   // round-to-nearest-even
    return (unsigned short)(u >> 16);
}
__device__ __forceinline__ float bf2f(unsigned short h) {
    unsigned u = ((unsigned)h) << 16;
    return __builtin_bit_cast(float, u);
}
__device__ __forceinline__ s16x8 cvt8(float4 a, float4 b) {
    s16x8 r;
    r[0] = (short)f2bf(a.x); r[1] = (short)f2bf(a.y);
    r[2] = (short)f2bf(a.z); r[3] = (short)f2bf(a.w);
    r[4] = (short)f2bf(b.x); r[5] = (short)f2bf(b.y);
    r[6] = (short)f2bf(b.z); r[7] = (short)f2bf(b.w);
    return r;
}

// Split-K GEMM: block b computes partial[i][j] = sum_{k in chunk b} x[i,k]*y[j,k].
// 1 block/CU, depth-2 register prefetch (stage_write waits only on loads
// issued a full iteration earlier -> load stream never stalls).
__global__ __launch_bounds__(THREADS) void gemm_splitk(
    const float* __restrict__ x, const float* __restrict__ y,
    const float* __restrict__ kern,
    unsigned int* __restrict__ ws32, float* __restrict__ out, int use_ws)
{
    __shared__ __align__(16) short lds[2][2][M_DIM][BK];   // 64 KiB

    const int t    = threadIdx.x;
    const long kb0 = (long)blockIdx.x * KC;

    // staging: thread t handles rows (t>>3), (t>>3)+64; 8-float group t&7
    const int srow = t >> 3;
    const int sg   = t & 7;
    const int wofs = (sg ^ (srow & 7)) * 8;   // swizzle ((srow+64)&7 == srow&7)

    const float* xa = x + (size_t)srow        * K_DIM + kb0 + sg * 8;
    const float* xb = x + (size_t)(srow + 64) * K_DIM + kb0 + sg * 8;
    const float* ya = y + (size_t)srow        * K_DIM + kb0 + sg * 8;
    const float* yb = y + (size_t)(srow + 64) * K_DIM + kb0 + sg * 8;

    // wave tile: 8 waves 2(row)x4(col); each wave 64x32 = 4x2 frags of 16x16
    const int wave = t >> 6;
    const int lane = t & 63;
    const int wr   = wave >> 2;
    const int wc   = wave & 3;
    const int l15  = lane & 15;
    const int l4   = lane >> 4;

    f32x4 acc[4][2] = {};
    float4 A0,A1,A2,A3,A4,A5,A6,A7;
    float4 B0,B1,B2,B3,B4,B5,B6,B7;

    #define STAGE_LOAD(R, kb)                                            \
        R##0 = *(const float4*)(xa + (kb)); R##1 = *(const float4*)(xa + (kb) + 4); \
        R##2 = *(const float4*)(xb + (kb)); R##3 = *(const float4*)(xb + (kb) + 4); \
        R##4 = *(const float4*)(ya + (kb)); R##5 = *(const float4*)(ya + (kb) + 4); \
        R##6 = *(const float4*)(yb + (kb)); R##7 = *(const float4*)(yb + (kb) + 4);

    #define STAGE_WRITE(R, buf)                                          \
        *(s16x8*)&lds[buf][0][srow     ][wofs] = cvt8(R##0, R##1);       \
        *(s16x8*)&lds[buf][0][srow + 64][wofs] = cvt8(R##2, R##3);       \
        *(s16x8*)&lds[buf][1][srow     ][wofs] = cvt8(R##4, R##5);       \
        *(s16x8*)&lds[buf][1][srow + 64][wofs] = cvt8(R##6, R##7);

    auto compute = [&](int buf) {
        #pragma unroll
        for (int ks = 0; ks < 2; ++ks) {
            s16x8 af[4], bf[2];
            const int g = ks * 4 + l4;
            #pragma unroll
            for (int m = 0; m < 4; ++m) {
                const int row = wr * 64 + m * 16 + l15;
                af[m] = *(const s16x8*)&lds[buf][0][row][(g ^ (row & 7)) * 8];
            }
            #pragma unroll
            for (int n = 0; n < 2; ++n) {
                const int row = wc * 32 + n * 16 + l15;
                bf[n] = *(const s16x8*)&lds[buf][1][row][(g ^ (row & 7)) * 8];
            }
            #pragma unroll
            for (int m = 0; m < 4; ++m)
                #pragma unroll
                for (int n = 0; n < 2; ++n)
                    acc[m][n] = __builtin_amdgcn_mfma_f32_16x16x32_bf16(
                        af[m], bf[n], acc[m][n], 0, 0, 0);
        }
    };

    STAGE_LOAD(A, 0)
    STAGE_LOAD(B, BK)
    STAGE_WRITE(A, 0)
    __syncthreads();

    #pragma unroll
    for (int s = 0; s < NSTEP; s += 2) {
        if (s + 2 < NSTEP) { STAGE_LOAD(A, (long)(s + 2) * BK) }
        compute(0);
        STAGE_WRITE(B, 1)
        __syncthreads();
        if (s + 3 < NSTEP) { STAGE_LOAD(B, (long)(s + 3) * BK) }
        compute(1);
        if (s + 2 < NSTEP) { STAGE_WRITE(A, 0) }
        __syncthreads();
    }

    if (use_ws) {
        // Fragment-native packed store: chunk c==m, uint4 =
        // {pack(acc[m][0],rp0), pack(acc[m][0],rp1),
        //  pack(acc[m][1],rp0), pack(acc[m][1],rp1)},
        // pack(...,rp) = bf16(acc[..][rp*2]) | bf16(acc[..][rp*2+1])<<16.
        // Slot j = (c*512+t)*4 + w  ->  i = c*4+w, gemm-thread = t.
        // 16B/lane, lane-consecutive: fully coalesced 1KB/wave store.
        uint4* wp4 = (uint4*)(ws32 + (size_t)blockIdx.x * WS_U32_PER_BLK);
        #pragma unroll
        for (int m = 0; m < 4; ++m) {
            uint4 v;
            v.x = (unsigned)f2bf(acc[m][0][0]) | ((unsigned)f2bf(acc[m][0][1]) << 16);
            v.y = (unsigned)f2bf(acc[m][0][2]) | ((unsigned)f2bf(acc[m][0][3]) << 16);
            v.z = (unsigned)f2bf(acc[m][1][0]) | ((unsigned)f2bf(acc[m][1][1]) << 16);
            v.w = (unsigned)f2bf(acc[m][1][2]) | ((unsigned)f2bf(acc[m][1][3]) << 16);
            wp4[m * 512 + t] = v;
        }
    } else {
        const float scale = kern[0] * (1.0f / 512.0f);
        #pragma unroll
        for (int m = 0; m < 4; ++m) {
            const int row = wr * 64 + m * 16 + l4 * 4;
            #pragma unroll
            for (int n = 0; n < 2; ++n) {
                const int col = wc * 32 + n * 16 + l15;
                #pragma unroll
                for (int r = 0; r < 4; ++r)
                    atomicAdd(out + (size_t)(row + r) * M_DIM + col,
                              acc[m][n][r] * scale);
            }
        }
    }
    #undef STAGE_LOAD
    #undef STAGE_WRITE
}

// 256 blocks x 256 threads: block rb reduces u32 slots [rb*32, rb*32+32)
// (= 64 outputs) over all 256 splits. uint4 loads: 128 B/thread.
__global__ __launch_bounds__(256) void reduce_k(
    const unsigned int* __restrict__ ws32, const float* __restrict__ kern,
    float* __restrict__ out)
{
    __shared__ float red[32][8][8];    // [split-chunk][uint4-slot][w*2+half]
    const int rb = blockIdx.x;
    const int t  = threadIdx.x;
    const int qi = t & 7;              // 8 uint4 slots = 32 u32
    const int sc = t >> 3;             // 32 split-chunks of 8 splits

    const uint4* rp = (const uint4*)(ws32 + (size_t)(sc * 8) * WS_U32_PER_BLK
                                          + rb * 32 + qi * 4);
    float a[8] = {};
    #pragma unroll
    for (int j = 0; j < 8; ++j) {
        uint4 v = rp[(size_t)j * (WS_U32_PER_BLK / 4)];
        a[0] += bf2f((unsigned short)(v.x & 0xffff));
        a[1] += bf2f((unsigned short)(v.x >> 16));
        a[2] += bf2f((unsigned short)(v.y & 0xffff));
        a[3] += bf2f((unsigned short)(v.y >> 16));
        a[4] += bf2f((unsigned short)(v.z & 0xffff));
        a[5] += bf2f((unsigned short)(v.z >> 16));
        a[6] += bf2f((unsigned short)(v.w & 0xffff));
        a[7] += bf2f((unsigned short)(v.w >> 16));
    }
    #pragma unroll
    for (int i = 0; i < 8; ++i) red[sc][qi][i] = a[i];
    __syncthreads();
    for (int off = 16; off > 0; off >>= 1) {
        if (sc < off) {
            #pragma unroll
            for (int i = 0; i < 8; ++i)
                red[sc][qi][i] += red[sc + off][qi][i];
        }
        __syncthreads();
    }
    if (t < 64) {
        // global slot j = rb*32 + (t>>1), half = t&1
        const int j    = rb * 32 + (t >> 1);
        const int half = t & 1;
        const int w    = j & 3;
        const int gt   = (j >> 2) & 511;          // gemm thread
        const int c    = j >> 11;                 // chunk == m
        const int m_   = c;
        const int n_   = w >> 1;
        const int rp_  = w & 1;
        const int wv   = gt >> 6, ln = gt & 63;
        const int row  = (wv >> 2) * 64 + m_ * 16 + (ln >> 4) * 4 + rp_ * 2 + half;
        const int col  = (wv & 3) * 32 + n_ * 16 + (ln & 15);
        const float scale = kern[0] * (1.0f / 512.0f);
        // red[0][ (t>>1)>>2 wait: qi = ((j - rb*32)>>2) = (t>>1)>>2 = t>>3 ]
        const float v = red[0][t >> 3][((t >> 1) & 3) * 2 + half];
        out[row * M_DIM + col] = v * scale + 0.1f;
    }
}

__global__ __launch_bounds__(256) void init_k(float* __restrict__ out) {
    out[blockIdx.x * 256 + threadIdx.x] = 0.1f;
}

extern "C" void kernel_launch(void* const* d_in, const int* in_sizes, int n_in,
                              void* d_out, int out_size, void* d_ws, size_t ws_size,
                              hipStream_t stream) {
    const float* x    = (const float*)d_in[0];
    const float* y    = (const float*)d_in[1];
    const float* kern = (const float*)d_in[2];
    float* out = (float*)d_out;

    const size_t need = (size_t)NSPLIT * WS_U32_PER_BLK * 4;   // 8 MiB
    if (ws_size >= need && d_ws != nullptr) {
        unsigned int* ws32 = (unsigned int*)d_ws;
        gemm_splitk<<<NSPLIT, THREADS, 0, stream>>>(x, y, kern, ws32, out, 1);
        reduce_k<<<256, 256, 0, stream>>>(ws32, kern, out);
    } else {
        init_k<<<OUT_N / 256, 256, 0, stream>>>(out);
        gemm_splitk<<<NSPLIT, THREADS, 0, stream>>>(x, y, kern, nullptr, out, 0);
    }
}